// Round 5
// baseline (3523.031 us; speedup 1.0000x reference)
//
#include <hip/hip_runtime.h>
#include <math.h>

#define RL(x) __builtin_amdgcn_readfirstlane(x)
#define NBLK 512

__device__ __forceinline__ float relu_(float v) { return v > 0.f ? v : 0.f; }

// Software grid barrier: monotonic arrive counter in global ws (memset to 0
// per launch). Release fence -> arrive -> relaxed spin -> acquire fence gives
// cross-XCD visibility per the HIP agent-scope memory model.
__device__ __forceinline__ void gbar(int* cnt, int target) {
  __syncthreads();
  if (threadIdx.x == 0) {
    __builtin_amdgcn_fence(__ATOMIC_RELEASE, "agent");
    __hip_atomic_fetch_add(cnt, 1, __ATOMIC_RELAXED, __HIP_MEMORY_SCOPE_AGENT);
    while (__hip_atomic_load(cnt, __ATOMIC_RELAXED, __HIP_MEMORY_SCOPE_AGENT) < target)
      __builtin_amdgcn_s_sleep(2);
    __builtin_amdgcn_fence(__ATOMIC_ACQUIRE, "agent");
  }
  __syncthreads();
}

// ===========================================================================
// Persistent mega-kernel, plain launch <<<512,256>>>, 2 blocks/CU.
// ~44 gbar()-separated phases replace 45 kernel launches.
// ===========================================================================
__global__ __launch_bounds__(256, 2) void k_mega(
    const float* __restrict__ x, const float* __restrict__ eps,
    const float* __restrict__ emb,
    const float* __restrict__ ew0, const float* __restrict__ ew0b,
    const float* __restrict__ ew1, const float* __restrict__ ew1b,
    const float* __restrict__ er0, const float* __restrict__ er0b,
    const float* __restrict__ elinw, const float* __restrict__ elinb,
    const float* __restrict__ dw0, const float* __restrict__ dw0b,
    const float* __restrict__ dw1, const float* __restrict__ dw1b,
    const float* __restrict__ dr0, const float* __restrict__ dr0b,
    const float* __restrict__ dlinw, const float* __restrict__ dlinb,
    float* __restrict__ out, float* __restrict__ ws)
{
  const int bid = blockIdx.x, tid = threadIdx.x;

  float* W1T    = ws + 0;        // 4096x256 (encoder)
  float* H2ALL  = ws + 0;        // 20x256x128 (decoder; overlays W1T)
  float* LINT   = ws + 1048576;  // 256x256
  float* DLINT  = ws + 1114112;  // 128x128
  float* EMBSQ  = ws + 1130496;  // 512
  float* H1A    = ws + 1131008;  // 256x4096
  float* H1B    = ws + 2179584;  // 256x4096
  float* Q      = ws + 3228160;  // 256x4096
  float* PARTS0 = ws + 4276736;  // 16x256x256
  float* PARTS1 = ws + 5325312;  // 16x256x256
  float* H1L0   = PARTS0;        // decoder overlay
  float* H1L1   = PARTS1;        // decoder overlay
  float* H2A    = ws + 6373888;  // 256x256
  float* H2B    = ws + 6439424;  // 256x256
  float* SCAL   = ws + 6504960;  // [0]=loss, [1]=kl
  float* COUNTS = ws + 6504962;  // 512
  float* PBEST  = ws + 6505474;  // 2x256x64
  int*   PIDX   = (int*)(ws + 6538242);  // 2x256x64
  int*   CNT    = (int*)(ws + 6571010);  // barrier counter (memset 0)

  __shared__ float sbuf[64 * 65];
  __shared__ float sd[256];
  __shared__ int   sk[256];
  __shared__ int   fk[64];
  __shared__ int   lhist[512];
  __shared__ float red[256];
  __shared__ float cur[128];

  int ep = 0;

  // ======================= Phase 0: prep =================================
  if (bid < 276) {
    const float* in; float* o_; int R, C, tr, tc;
    if (bid < 256)      { in = ew1;   o_ = W1T;   R = 256; C = 4096; tr = bid >> 6;         tc = bid & 63; }
    else if (bid < 272) { in = elinw; o_ = LINT;  R = 256; C = 256;  tr = (bid - 256) >> 2; tc = (bid - 256) & 3; }
    else                { in = dlinw; o_ = DLINT; R = 128; C = 128;  tr = (bid - 272) >> 1; tc = (bid - 272) & 1; }
    int r0_ = tr * 64, c0 = tc * 64;
    int lane = tid & 63, grp = tid >> 6;
    for (int pp = 0; pp < 16; ++pp) {
      int rr = pp * 4 + grp;
      sbuf[rr * 65 + lane] = in[(r0_ + rr) * C + c0 + lane];
    }
    __syncthreads();
    for (int pp = 0; pp < 16; ++pp) {
      int cc = pp * 4 + grp;
      o_[(c0 + cc) * R + r0_ + lane] = sbuf[lane * 65 + cc];
    }
  } else if (bid < 278) {
    int k = (bid - 276) * 256 + tid;
    const float* e = emb + k * 64;
    float s0 = 0, s1 = 0, s2 = 0, s3 = 0;
    #pragma unroll
    for (int c = 0; c < 64; c += 4) {
      s0 += e[c] * e[c]; s1 += e[c+1] * e[c+1];
      s2 += e[c+2] * e[c+2]; s3 += e[c+3] * e[c+3];
    }
    EMBSQ[k] = (s0 + s1) + (s2 + s3);
  } else if (bid == 278) {
    if (tid < 2) SCAL[tid] = 0.f;
    for (int j = tid; j < 512; j += 256) COUNTS[j] = 0.f;
  }
  gbar(CNT, NBLK * ++ep);

  // ======================= Encoder: phases t = 0..19 =====================
  for (int t = 0; t < 20; ++t) {
    const float* h1i = (t & 1) ? H1A : H1B;
    float* h1o       = (t & 1) ? H1B : H1A;
    float* po        = ((t - 1) & 1) ? PARTS1 : PARTS0;
    const float* pi  = (t & 1) ? PARTS1 : PARTS0;
    float* h2o       = (t & 1) ? H2B : H2A;
    const float* h2i = (t & 1) ? H2A : H2B;
    if (bid >= 256) {           // ---- contract_{t-1}: 256 blocks, acc[16] ----
      if (t >= 1) {
        int cid = bid - 256;
        int ks = cid & 15, bt = cid >> 4;
        int kc = ks * 256, b0 = bt * 16;
        float acc[16];
        #pragma unroll
        for (int q = 0; q < 16; ++q) acc[q] = 0.f;
        const float* wp = W1T + kc * 256 + tid;
        const float* hp = h1i + b0 * 4096 + kc;
        for (int k = 0; k < 256; k += 4) {
          float w0v = wp[k * 256], w1v = wp[(k+1) * 256];
          float w2v = wp[(k+2) * 256], w3v = wp[(k+3) * 256];
          #pragma unroll
          for (int q = 0; q < 16; ++q) {
            const float* hr = hp + q * 4096 + k;   // uniform -> s_load
            acc[q] += hr[0] * w0v + hr[1] * w1v + hr[2] * w2v + hr[3] * w3v;
          }
        }
        float* pb = po + ks * 65536 + b0 * 256 + tid;
        #pragma unroll
        for (int q = 0; q < 16; ++q) pb[q * 256] = acc[q];
      }
    } else {
      int b = bid;
      if (t >= 2) {             // ---- h2_{t-2} epilogue ----
        int o = tid;
        float s = ew1b[o];
        const float* pp = pi + b * 256 + o;
        #pragma unroll
        for (int ks2 = 0; ks2 < 16; ++ks2) s += pp[ks2 * 65536];
        float h2h = relu_(s);
        if (t >= 3) {
          const float* h2r = h2i + b * 256;
          float a0 = 0, a1 = 0;
          for (int j = 0; j < 256; j += 2) {
            a0 += LINT[j * 256 + o] * h2r[j];
            a1 += LINT[(j + 1) * 256 + o] * h2r[j + 1];
          }
          h2h = relu_(h2h + a0 + a1 + elinb[o]);
        }
        h2o[b * 256 + o] = h2h;
      }
      if (t <= 18) {            // ---- h1_t = relu(conv0 [+ rec]) ----
        int p = tid & 63;
        int o0 = RL(tid >> 6) * 16;
        int i = p >> 3, j = p & 7;
        const float* xb = x + ((b * 19 + t) * 3) * 576 + (i * 3) * 24 + j * 3;
        float xv[27];
        #pragma unroll
        for (int c = 0; c < 3; ++c)
          #pragma unroll
          for (int ki = 0; ki < 3; ++ki)
            #pragma unroll
            for (int kj = 0; kj < 3; ++kj)
              xv[c * 9 + ki * 3 + kj] = xb[c * 576 + ki * 24 + kj];
        float acc[16];
        #pragma unroll
        for (int q = 0; q < 16; ++q) {
          float a = ew0b[o0 + q] + (t > 0 ? er0b[o0 + q] : 0.f);
          const float* wr = ew0 + (o0 + q) * 27;   // uniform -> s_load
          float c0 = 0, c1 = 0, c2 = 0;
          #pragma unroll
          for (int m = 0; m < 27; m += 3) {
            c0 += xv[m] * wr[m]; c1 += xv[m+1] * wr[m+1]; c2 += xv[m+2] * wr[m+2];
          }
          acc[q] = a + c0 + c1 + c2;
        }
        if (t > 0) {
          const float* hb = h1i + b * 4096 + p;
          for (int c = 0; c < 64; c += 4) {
            float h0 = hb[c * 64], h1v = hb[(c+1) * 64];
            float h2v = hb[(c+2) * 64], h3v = hb[(c+3) * 64];
            #pragma unroll
            for (int q = 0; q < 16; ++q) {
              const float* rr = er0 + (o0 + q) * 64 + c;  // uniform -> s_load
              acc[q] += h0 * rr[0] + h1v * rr[1] + h2v * rr[2] + h3v * rr[3];
            }
          }
        }
        float* ob = h1o + b * 4096 + p;
        #pragma unroll
        for (int q = 0; q < 16; ++q) ob[(o0 + q) * 64] = relu_(acc[q]);
      }
    }
    gbar(CNT, NBLK * ++ep);
  }

  // ==== Phase: h2_18 epilogue (0..255) || argmin half 1 (256..511) =======
  if (bid < 256) {
    int b = bid, o = tid;
    float s = ew1b[o];
    const float* pp = PARTS0 + b * 256 + o;    // contract_18
    #pragma unroll
    for (int ks2 = 0; ks2 < 16; ++ks2) s += pp[ks2 * 65536];
    float h2h = relu_(s);
    const float* h2r = H2B + b * 256;          // h2_17
    float a0 = 0, a1 = 0;
    for (int jj = 0; jj < 256; jj += 2) {
      a0 += LINT[jj * 256 + o] * h2r[jj];
      a1 += LINT[(jj + 1) * 256 + o] * h2r[jj + 1];
    }
    H2A[b * 256 + o] = relu_(h2h + a0 + a1 + elinb[o]);   // h2_18
  } else {
    int b = bid - 256;
    int p = tid & 63, kg = RL(tid >> 6);
    float f[64];
    const float* hb = H1A + b * 4096 + p;
    #pragma unroll
    for (int c = 0; c < 64; ++c) f[c] = hb[c * 64];
    float best = 3.4e38f; int bk = 0;
    int kbeg = 256 + kg * 64;
    for (int k = kbeg; k < kbeg + 64; ++k) {
      const float* er = emb + k * 64;          // uniform -> s_load
      float d0 = 0, d1 = 0, d2 = 0, d3 = 0;
      #pragma unroll
      for (int c = 0; c < 64; c += 4) {
        d0 += f[c] * er[c];     d1 += f[c+1] * er[c+1];
        d2 += f[c+2] * er[c+2]; d3 += f[c+3] * er[c+3];
      }
      float d = EMBSQ[k] - 2.f * ((d0 + d1) + (d2 + d3));
      if (d < best) { best = d; bk = k; }
    }
    sd[tid] = best; sk[tid] = bk;
    __syncthreads();
    if (tid < 64) {
      float bb = sd[tid]; int kk = sk[tid];
      #pragma unroll
      for (int g = 1; g < 4; ++g) {
        float dg = sd[g * 64 + tid];
        if (dg < bb) { bb = dg; kk = sk[g * 64 + tid]; }
      }
      PBEST[16384 + b * 64 + tid] = bb;
      PIDX [16384 + b * 64 + tid] = kk;
    }
  }
  gbar(CNT, NBLK * ++ep);

  // ==== Phase: argmin half 0 (0..255) || KL + h2 chain (256..511) ========
  if (bid < 256) {
    int b = bid;
    int p = tid & 63, kg = RL(tid >> 6);
    float f[64];
    const float* hb = H1A + b * 4096 + p;
    #pragma unroll
    for (int c = 0; c < 64; ++c) f[c] = hb[c * 64];
    float best = 3.4e38f; int bk = 0;
    int kbeg = kg * 64;
    for (int k = kbeg; k < kbeg + 64; ++k) {
      const float* er = emb + k * 64;          // uniform -> s_load
      float d0 = 0, d1 = 0, d2 = 0, d3 = 0;
      #pragma unroll
      for (int c = 0; c < 64; c += 4) {
        d0 += f[c] * er[c];     d1 += f[c+1] * er[c+1];
        d2 += f[c+2] * er[c+2]; d3 += f[c+3] * er[c+3];
      }
      float d = EMBSQ[k] - 2.f * ((d0 + d1) + (d2 + d3));
      if (d < best) { best = d; bk = k; }
    }
    sd[tid] = best; sk[tid] = bk;
    __syncthreads();
    if (tid < 64) {
      float bb = sd[tid]; int kk = sk[tid];
      #pragma unroll
      for (int g = 1; g < 4; ++g) {
        float dg = sd[g * 64 + tid];
        if (dg < bb) { bb = dg; kk = sk[g * 64 + tid]; }
      }
      PBEST[b * 64 + tid] = bb;
      PIDX [b * 64 + tid] = kk;
    }
  } else {
    int b = bid - 256, j = tid;
    if (j < 128) {
      float mu = H2A[b * 256 + j];
      float lv = H2A[b * 256 + 128 + j];
      float term = 0.5f * (expf(lv) + mu * mu - 1.0f - lv);
      float hs = mu + expf(0.5f * lv) * eps[b * 128 + j];
      red[j] = term; cur[j] = hs;
    }
    __syncthreads();
    for (int s = 64; s > 0; s >>= 1) {
      if (j < s) red[j] += red[j + s];
      __syncthreads();
    }
    if (j == 0) atomicAdd(&SCAL[1], red[0]);
    for (int s = 0; s < 20; ++s) {
      float v = 0.f;
      if (j < 128) {
        float a0 = 0, a1 = 0;
        for (int jj = 0; jj < 128; jj += 2) {
          a0 += DLINT[jj * 128 + j] * cur[jj];
          a1 += DLINT[(jj + 1) * 128 + j] * cur[jj + 1];
        }
        v = relu_(a0 + a1 + dlinb[j]);
      }
      __syncthreads();
      if (j < 128) {
        cur[j] = v;
        H2ALL[s * 32768 + b * 128 + j] = v;
      }
      __syncthreads();
    }
  }
  gbar(CNT, NBLK * ++ep);

  // ==== Phase: VQ stats (0..255) || h1l_0 GEMM (256..511) ================
  if (bid < 256) {
    int b = bid;
    for (int j = tid; j < 512; j += 256) lhist[j] = 0;
    __syncthreads();                 // zero visible before atomics (R3 race fix)
    if (tid < 64) {
      float b0v = PBEST[b * 64 + tid];
      float b1v = PBEST[16384 + b * 64 + tid];
      int k0 = PIDX[b * 64 + tid], k1 = PIDX[16384 + b * 64 + tid];
      int kk = (b1v < b0v) ? k1 : k0;
      fk[tid] = kk;
      atomicAdd(&lhist[kk], 1);
    }
    __syncthreads();
    int p = tid & 63, cgi = tid >> 6;
    int kk = fk[p];
    const float* eb = emb + kk * 64 + cgi * 16;
    const float* hz = H1A + b * 4096 + cgi * 1024 + p;
    float* qb = Q + b * 4096 + cgi * 1024 + p;
    float ls = 0;
    #pragma unroll
    for (int c = 0; c < 16; ++c) {
      float e = eb[c];
      float z = hz[c * 64];
      float d = e - z;
      ls += d * d;
      qb[c * 64] = e;
    }
    red[tid] = ls;
    __syncthreads();
    for (int s = 128; s > 0; s >>= 1) { if (tid < s) red[tid] += red[tid + s]; __syncthreads(); }
    if (tid == 0) atomicAdd(&SCAL[0], red[0]);
    for (int j = tid; j < 512; j += 256) {
      int h = lhist[j];
      if (h > 0) atomicAdd(&COUNTS[j], (float)h);
    }
  } else {
    int cid = bid - 256;
    int nc = cid & 15, bt = cid >> 4;
    int n = nc * 256 + tid, b0 = bt * 16;
    const float* hp = H2ALL + b0 * 128;        // H2ALL[0]
    float acc[16];
    #pragma unroll
    for (int q = 0; q < 16; ++q) acc[q] = 0.f;
    for (int j = 0; j < 128; j += 4) {
      float w0v = dw1[j * 4096 + n], w1v = dw1[(j+1) * 4096 + n];
      float w2v = dw1[(j+2) * 4096 + n], w3v = dw1[(j+3) * 4096 + n];
      #pragma unroll
      for (int q = 0; q < 16; ++q) {
        const float* hr = hp + q * 128 + j;    // uniform -> s_load
        acc[q] += hr[0] * w0v + hr[1] * w1v + hr[2] * w2v + hr[3] * w3v;
      }
    }
    float* ob = H1L0 + b0 * 4096 + n;
    #pragma unroll
    for (int q = 0; q < 16; ++q) ob[q * 4096] = acc[q];
  }
  gbar(CNT, NBLK * ++ep);

  // ======================= Decoder: phases d = 1..20 =====================
  for (int d = 1; d <= 20; ++d) {
    int s = d - 1;
    float* h1l_o       = (d & 1) ? H1L1 : H1L0;
    const float* h1l_i = (d & 1) ? H1L0 : H1L1;
    const float* h1i   = (s <= 0) ? Q : (((s - 1) & 1) ? H1B : H1A);
    float* h1o         = (s & 1) ? H1B : H1A;
    if (bid >= 256) {           // ---- h1l_d GEMM: 256 blocks ----
      if (d <= 19) {
        int cid = bid - 256;
        int nc = cid & 15, bt = cid >> 4;
        int n = nc * 256 + tid, b0 = bt * 16;
        const float* hp = H2ALL + d * 32768 + b0 * 128;
        float acc[16];
        #pragma unroll
        for (int q = 0; q < 16; ++q) acc[q] = 0.f;
        for (int j = 0; j < 128; j += 4) {
          float w0v = dw1[j * 4096 + n], w1v = dw1[(j+1) * 4096 + n];
          float w2v = dw1[(j+2) * 4096 + n], w3v = dw1[(j+3) * 4096 + n];
          #pragma unroll
          for (int q = 0; q < 16; ++q) {
            const float* hr = hp + q * 128 + j;   // uniform -> s_load
            acc[q] += hr[0] * w0v + hr[1] * w1v + hr[2] * w2v + hr[3] * w3v;
          }
        }
        float* ob = h1l_o + b0 * 4096 + n;
        #pragma unroll
        for (int q = 0; q < 16; ++q) ob[q * 4096] = acc[q];
      }
    } else {                    // ---- h1 recurrence + emit ----
      int b = bid;
      int p = tid & 63;
      int o0 = RL(tid >> 6) * 16;
      float acc[16];
      #pragma unroll
      for (int q = 0; q < 16; ++q) acc[q] = dr0b[o0 + q] + dw1b[o0 + q];
      const float* hb = h1i + b * 4096 + p;
      for (int c = 0; c < 64; c += 4) {
        float h0 = hb[c * 64], h1v = hb[(c+1) * 64];
        float h2v = hb[(c+2) * 64], h3v = hb[(c+3) * 64];
        #pragma unroll
        for (int q = 0; q < 16; ++q) {
          const float* rr = dr0 + (o0 + q) * 64 + c;   // uniform -> s_load
          acc[q] += h0 * rr[0] + h1v * rr[1] + h2v * rr[2] + h3v * rr[3];
        }
      }
      const float* lb = h1l_i + b * 4096 + p;
      float* ob = h1o + b * 4096 + p;
      #pragma unroll
      for (int q = 0; q < 16; ++q) {
        float v = relu_(acc[q] + lb[(o0 + q) * 64]);
        ob[(o0 + q) * 64] = v;
        sbuf[(o0 + q) * 65 + p] = v;
      }
      __syncthreads();
      int t = d - 2;
      if (t >= 0) {
        int mbase = RL(tid >> 6) * 7;
        float a[7];
        #pragma unroll
        for (int qq = 0; qq < 7; ++qq) a[qq] = 0.f;
        for (int c = 0; c < 64; ++c) {
          float hv = sbuf[c * 65 + p];
          const float* wr = dw0 + c * 27 + mbase;   // uniform -> s_load
          #pragma unroll
          for (int qq = 0; qq < 7; ++qq)
            if (mbase + qq < 27) a[qq] += hv * wr[qq];
        }
        int hrow = p >> 3, wcol = p & 7;
        #pragma unroll
        for (int qq = 0; qq < 7; ++qq) {
          int m = mbase + qq;
          if (m < 27) {
            int o3 = m / 9, r = m % 9, ki = r / 3, kj = r % 3;
            float v = a[qq] + dw0b[o3];
            v = v > 0.f ? v : expm1f(v);   // ELU alpha=1
            out[2 + ((b * 19 + t) * 3 + o3) * 576 + (hrow * 3 + ki) * 24 + (wcol * 3 + kj)] = v;
          }
        }
      }
      __syncthreads();   // sbuf reused next iteration
    }
    gbar(CNT, NBLK * ++ep);
  }

  // ======================= Finalize ======================================
  if (bid == 0) {
    float e = 0.f;
    for (int u = tid; u < 512; u += 256) {
      float avg = COUNTS[u] * (1.0f / 16384.0f);
      e += avg * logf(avg + 1e-10f);
    }
    red[tid] = e;
    __syncthreads();
    for (int s = 128; s > 0; s >>= 1) { if (tid < s) red[tid] += red[tid + s]; __syncthreads(); }
    if (tid == 0) {
      out[0] = 0.25f * SCAL[0] * (1.0f / 1048576.0f);
      out[1] = SCAL[1] * (1.0f / 256.0f);
      out[2 + 8404992] = expf(-red[0]);
    }
  }
}

// ---------------------------------------------------------------------------
extern "C" void kernel_launch(void* const* d_in, const int* in_sizes, int n_in,
                              void* d_out, int out_size, void* d_ws, size_t ws_size,
                              hipStream_t stream)
{
  const float* x     = (const float*)d_in[0];
  const float* eps   = (const float*)d_in[1];
  const float* emb   = (const float*)d_in[2];
  const float* ew0   = (const float*)d_in[3];
  const float* ew0b  = (const float*)d_in[4];
  const float* ew1   = (const float*)d_in[5];
  const float* ew1b  = (const float*)d_in[6];
  const float* er0   = (const float*)d_in[7];
  const float* er0b  = (const float*)d_in[8];
  const float* elinw = (const float*)d_in[9];
  const float* elinb = (const float*)d_in[10];
  const float* dw0   = (const float*)d_in[11];
  const float* dw0b  = (const float*)d_in[12];
  const float* dw1   = (const float*)d_in[13];
  const float* dw1b  = (const float*)d_in[14];
  const float* dr0   = (const float*)d_in[15];
  const float* dr0b  = (const float*)d_in[16];
  const float* dlinw = (const float*)d_in[17];
  const float* dlinb = (const float*)d_in[18];
  float* out = (float*)d_out;
  float* ws  = (float*)d_ws;

  // zero the barrier counter (ws is re-poisoned to 0xAA before every launch)
  hipMemsetAsync(ws + 6571010, 0, sizeof(int), stream);

  k_mega<<<NBLK, 256, 0, stream>>>(x, eps, emb, ew0, ew0b, ew1, ew1b,
                                   er0, er0b, elinw, elinb, dw0, dw0b,
                                   dw1, dw1b, dr0, dr0b, dlinw, dlinb,
                                   out, ws);
}

// Round 6
// 1468.847 us; speedup vs baseline: 2.3985x; 2.3985x over previous
//
#include <hip/hip_runtime.h>
#include <math.h>

#define RL(x) __builtin_amdgcn_readfirstlane(x)

__device__ __forceinline__ float relu_(float v) { return v > 0.f ? v : 0.f; }

// ---------------------------------------------------------------------------
// Prep: transposes + |emb|^2 + zero scalars/counts (grid 279)
// ---------------------------------------------------------------------------
__global__ __launch_bounds__(256) void k_prep(
    const float* __restrict__ w1, const float* __restrict__ linw,
    const float* __restrict__ dlinw, const float* __restrict__ emb,
    float* __restrict__ w1T, float* __restrict__ linT,
    float* __restrict__ dlinT, float* __restrict__ embsq,
    float* __restrict__ scal, float* __restrict__ counts)
{
  int bid = blockIdx.x;
  if (bid == 278) {
    if (threadIdx.x < 2) scal[threadIdx.x] = 0.f;
    for (int j = threadIdx.x; j < 512; j += 256) counts[j] = 0.f;
    return;
  }
  if (bid >= 276) {
    int k = (bid - 276) * 256 + threadIdx.x;
    const float* e = emb + k * 64;
    float s0 = 0, s1 = 0, s2 = 0, s3 = 0;
    #pragma unroll
    for (int c = 0; c < 64; c += 4) {
      s0 += e[c] * e[c]; s1 += e[c+1] * e[c+1];
      s2 += e[c+2] * e[c+2]; s3 += e[c+3] * e[c+3];
    }
    embsq[k] = (s0 + s1) + (s2 + s3);
    return;
  }
  __shared__ float buf[64 * 65];
  const float* in; float* out; int R, C, tr, tc;
  if (bid < 256)      { in = w1;    out = w1T;   R = 256; C = 4096; tr = bid >> 6;         tc = bid & 63; }
  else if (bid < 272) { in = linw;  out = linT;  R = 256; C = 256;  tr = (bid - 256) >> 2; tc = (bid - 256) & 3; }
  else                { in = dlinw; out = dlinT; R = 128; C = 128;  tr = (bid - 272) >> 1; tc = (bid - 272) & 1; }
  int r0 = tr * 64, c0 = tc * 64;
  int lane = threadIdx.x & 63, grp = threadIdx.x >> 6;
  for (int pp = 0; pp < 16; ++pp) {
    int rr = pp * 4 + grp;
    buf[rr * 65 + lane] = in[(r0 + rr) * C + c0 + lane];
  }
  __syncthreads();
  for (int pp = 0; pp < 16; ++pp) {
    int cc = pp * 4 + grp;
    out[(c0 + cc) * R + r0 + lane] = buf[lane * 65 + cc];
  }
}

// ---------------------------------------------------------------------------
// Encoder step E_t, grid 1024:
//  blocks 0..511   (b=bid>>1, og=bid&1): h2_{t-2} epilogue half + h1_t half
//  blocks 512..1023: contract_{t-1}, 16 ksplit x 32 btile (8 batches, acc[8])
// ---------------------------------------------------------------------------
__global__ __launch_bounds__(256) void k_enc(
    const float* __restrict__ x, int t,
    const float* __restrict__ w0, const float* __restrict__ w0b,
    const float* __restrict__ r0, const float* __restrict__ r0b,
    const float* __restrict__ h1_in, float* __restrict__ h1_out,
    const float* __restrict__ w1T, float* __restrict__ parts_out,
    const float* __restrict__ parts_in, const float* __restrict__ w1b,
    const float* __restrict__ linT, const float* __restrict__ linb,
    const float* __restrict__ h2_in, float* __restrict__ h2_out)
{
  int bid = blockIdx.x, tid = threadIdx.x;
  if (bid >= 512) {           // ---- contract_{t-1} ----
    if (t == 0) return;
    int cid = bid - 512;
    int ks = cid & 15, bt = cid >> 4;        // bt 0..31
    int kc = ks * 256, b0 = bt * 8;
    float acc[8];
    #pragma unroll
    for (int q = 0; q < 8; ++q) acc[q] = 0.f;
    const float* wp = w1T + kc * 256 + tid;
    const float* hp = h1_in + b0 * 4096 + kc;
    for (int k = 0; k < 256; k += 4) {
      float w0v = wp[k * 256], w1v = wp[(k+1) * 256];
      float w2v = wp[(k+2) * 256], w3v = wp[(k+3) * 256];
      #pragma unroll
      for (int q = 0; q < 8; ++q) {
        const float* hr = hp + q * 4096 + k;   // uniform -> s_load_dwordx4
        acc[q] += hr[0] * w0v + hr[1] * w1v + hr[2] * w2v + hr[3] * w3v;
      }
    }
    float* pb = parts_out + ks * 65536 + b0 * 256 + tid;
    #pragma unroll
    for (int q = 0; q < 8; ++q) pb[q * 256] = acc[q];
    return;
  }
  int b = bid >> 1, og = bid & 1;
  if (t >= 2 && tid < 128) {  // ---- h2_{t-2} epilogue (128 o's per block) ----
    int o = og * 128 + tid;
    float s = w1b[o];
    const float* pp = parts_in + b * 256 + o;
    #pragma unroll
    for (int ks2 = 0; ks2 < 16; ++ks2) s += pp[ks2 * 65536];
    float h2h = relu_(s);
    if (t >= 3) {
      const float* h2r = h2_in + b * 256;
      float a0 = 0, a1 = 0;
      for (int j = 0; j < 256; j += 2) {
        a0 += linT[j * 256 + o] * h2r[j];
        a1 += linT[(j + 1) * 256 + o] * h2r[j + 1];
      }
      h2h = relu_(h2h + a0 + a1 + linb[o]);
    }
    h2_out[b * 256 + o] = h2h;
  }
  if (t > 18) return;
  // ---- h1_t half: 32 o-rows per block (8 per wavegroup) ----
  int p = tid & 63;
  int o0 = og * 32 + RL(tid >> 6) * 8;
  int i = p >> 3, j = p & 7;
  const float* xb = x + ((b * 19 + t) * 3) * 576 + (i * 3) * 24 + j * 3;
  float xv[27];
  #pragma unroll
  for (int c = 0; c < 3; ++c)
    #pragma unroll
    for (int ki = 0; ki < 3; ++ki)
      #pragma unroll
      for (int kj = 0; kj < 3; ++kj)
        xv[c * 9 + ki * 3 + kj] = xb[c * 576 + ki * 24 + kj];
  float acc[8];
  #pragma unroll
  for (int q = 0; q < 8; ++q) {
    float a = w0b[o0 + q] + (t > 0 ? r0b[o0 + q] : 0.f);
    const float* wr = w0 + (o0 + q) * 27;   // uniform -> s_load
    float c0 = 0, c1 = 0, c2 = 0;
    #pragma unroll
    for (int m = 0; m < 27; m += 3) {
      c0 += xv[m] * wr[m]; c1 += xv[m+1] * wr[m+1]; c2 += xv[m+2] * wr[m+2];
    }
    acc[q] = a + c0 + c1 + c2;
  }
  if (t > 0) {
    const float* hb = h1_in + b * 4096 + p;
    for (int c = 0; c < 64; c += 4) {
      float h0 = hb[c * 64], h1v = hb[(c+1) * 64];
      float h2v = hb[(c+2) * 64], h3v = hb[(c+3) * 64];
      #pragma unroll
      for (int q = 0; q < 8; ++q) {
        const float* rr = r0 + (o0 + q) * 64 + c;  // uniform -> s_load
        acc[q] += h0 * rr[0] + h1v * rr[1] + h2v * rr[2] + h3v * rr[3];
      }
    }
  }
  float* ob = h1_out + b * 4096 + p;
  #pragma unroll
  for (int q = 0; q < 8; ++q) ob[(o0 + q) * 64] = relu_(acc[q]);
}

// ---------------------------------------------------------------------------
// Argmin quarters (blocks 0..1023: qtr=bid>>8, b=bid&255, 32 codes/wavegroup)
// + h2_18 epilogue (blocks 1024..1279).
// ---------------------------------------------------------------------------
__global__ __launch_bounds__(256) void k_argmin(
    const float* __restrict__ h1, const float* __restrict__ emb,
    const float* __restrict__ embsq,
    const float* __restrict__ parts, const float* __restrict__ w1b,
    const float* __restrict__ linT, const float* __restrict__ linb,
    const float* __restrict__ h2_in, float* __restrict__ h2_out,
    float* __restrict__ pbest, int* __restrict__ pidx)
{
  int bid = blockIdx.x, tid = threadIdx.x;
  if (bid >= 1024) {          // ---- h2_18 epilogue ----
    int b = bid - 1024, o = tid;
    float s = w1b[o];
    const float* pp = parts + b * 256 + o;
    #pragma unroll
    for (int ks2 = 0; ks2 < 16; ++ks2) s += pp[ks2 * 65536];
    float h2h = relu_(s);
    const float* h2r = h2_in + b * 256;
    float a0 = 0, a1 = 0;
    for (int jj = 0; jj < 256; jj += 2) {
      a0 += linT[jj * 256 + o] * h2r[jj];
      a1 += linT[(jj + 1) * 256 + o] * h2r[jj + 1];
    }
    h2_out[b * 256 + o] = relu_(h2h + a0 + a1 + linb[o]);
    return;
  }
  __shared__ float sd[256];
  __shared__ int   sk[256];
  int qtr = bid >> 8, b = bid & 255;
  int p = tid & 63, kg = RL(tid >> 6);
  float f[64];
  const float* hb = h1 + b * 4096 + p;
  #pragma unroll
  for (int c = 0; c < 64; ++c) f[c] = hb[c * 64];
  float best = 3.4e38f; int bk = 0;
  int kbeg = qtr * 128 + kg * 32;
  for (int k = kbeg; k < kbeg + 32; ++k) {
    const float* er = emb + k * 64;          // uniform -> s_load
    float d0 = 0, d1 = 0, d2 = 0, d3 = 0;
    #pragma unroll
    for (int c = 0; c < 64; c += 4) {
      d0 += f[c] * er[c];     d1 += f[c+1] * er[c+1];
      d2 += f[c+2] * er[c+2]; d3 += f[c+3] * er[c+3];
    }
    float d = embsq[k] - 2.f * ((d0 + d1) + (d2 + d3));
    if (d < best) { best = d; bk = k; }
  }
  sd[tid] = best; sk[tid] = bk;
  __syncthreads();
  if (tid < 64) {
    float bb = sd[tid]; int kk = sk[tid];
    #pragma unroll
    for (int g = 1; g < 4; ++g) {
      float dg = sd[g * 64 + tid];
      if (dg < bb) { bb = dg; kk = sk[g * 64 + tid]; }
    }
    pbest[qtr * 16384 + b * 64 + tid] = bb;
    pidx [qtr * 16384 + b * 64 + tid] = kk;
  }
}

// ---------------------------------------------------------------------------
// KL + reparam + decoder h2 chain (grid 256, b=bid)
// ---------------------------------------------------------------------------
__global__ __launch_bounds__(256) void k_mid(
    const float* __restrict__ h2, const float* __restrict__ eps,
    float* __restrict__ kl_sum,
    const float* __restrict__ dlinT, const float* __restrict__ dlinb,
    float* __restrict__ h2all)
{
  __shared__ float cur[128];
  __shared__ float red[128];
  int b = blockIdx.x, j = threadIdx.x;
  if (j < 128) {
    float mu = h2[b * 256 + j];
    float lv = h2[b * 256 + 128 + j];
    float term = 0.5f * (expf(lv) + mu * mu - 1.0f - lv);
    float hs = mu + expf(0.5f * lv) * eps[b * 128 + j];
    red[j] = term; cur[j] = hs;
  }
  __syncthreads();
  for (int s = 64; s > 0; s >>= 1) {
    if (j < s) red[j] += red[j + s];
    __syncthreads();
  }
  if (j == 0) atomicAdd(kl_sum, red[0]);
  for (int s = 0; s < 20; ++s) {
    float v = 0.f;
    if (j < 128) {
      float a0 = 0, a1 = 0;
      for (int jj = 0; jj < 128; jj += 2) {
        a0 += dlinT[jj * 128 + j] * cur[jj];
        a1 += dlinT[(jj + 1) * 128 + j] * cur[jj + 1];
      }
      v = relu_(a0 + a1 + dlinb[j]);
    }
    __syncthreads();
    if (j < 128) {
      cur[j] = v;
      h2all[s * 32768 + b * 128 + j] = v;
    }
    __syncthreads();
  }
}

// ---------------------------------------------------------------------------
// VQ stats (blocks 0..255: 4-quarter merge + Q gather + loss + hist)
// + h1l_0 GEMM (blocks 256..767)
// ---------------------------------------------------------------------------
__global__ __launch_bounds__(256) void k_dec0(
    const float* __restrict__ h1, const float* __restrict__ emb,
    const float* __restrict__ pbest, const int* __restrict__ pidx,
    float* __restrict__ Q, float* __restrict__ counts,
    float* __restrict__ loss_sum,
    const float* __restrict__ h2all, const float* __restrict__ dw1,
    float* __restrict__ h1l0)
{
  int bid = blockIdx.x, tid = threadIdx.x;
  if (bid >= 256) {           // ---- h1l_0 ----
    int cid = bid - 256;
    int nc = cid & 15, bt = cid >> 4;
    int n = nc * 256 + tid, b0 = bt * 8;
    const float* hp = h2all + b0 * 128;      // H2ALL[0]
    float acc[8];
    #pragma unroll
    for (int q = 0; q < 8; ++q) acc[q] = 0.f;
    for (int j = 0; j < 128; j += 4) {
      float w0v = dw1[j * 4096 + n], w1v = dw1[(j+1) * 4096 + n];
      float w2v = dw1[(j+2) * 4096 + n], w3v = dw1[(j+3) * 4096 + n];
      #pragma unroll
      for (int q = 0; q < 8; ++q) {
        const float* hr = hp + q * 128 + j;  // uniform -> s_load
        acc[q] += hr[0] * w0v + hr[1] * w1v + hr[2] * w2v + hr[3] * w3v;
      }
    }
    float* ob = h1l0 + b0 * 4096 + n;
    #pragma unroll
    for (int q = 0; q < 8; ++q) ob[q * 4096] = acc[q];
    return;
  }
  __shared__ int   fk[64];
  __shared__ int   lhist[512];
  __shared__ float red[256];
  int b = bid;
  for (int j = tid; j < 512; j += 256) lhist[j] = 0;
  __syncthreads();
  if (tid < 64) {
    float bb = pbest[b * 64 + tid];
    int   kk = pidx [b * 64 + tid];
    #pragma unroll
    for (int q = 1; q < 4; ++q) {
      float dq = pbest[q * 16384 + b * 64 + tid];
      if (dq < bb) { bb = dq; kk = pidx[q * 16384 + b * 64 + tid]; }
    }
    fk[tid] = kk;
    atomicAdd(&lhist[kk], 1);
  }
  __syncthreads();
  int p = tid & 63, cgi = tid >> 6;
  int kk = fk[p];
  const float* eb = emb + kk * 64 + cgi * 16;
  const float* hz = h1 + b * 4096 + cgi * 1024 + p;
  float* qb = Q + b * 4096 + cgi * 1024 + p;
  float ls = 0;
  #pragma unroll
  for (int c = 0; c < 16; ++c) {
    float e = eb[c];
    float z = hz[c * 64];
    float d = e - z;
    ls += d * d;
    qb[c * 64] = e;
  }
  red[tid] = ls;
  __syncthreads();
  for (int s = 128; s > 0; s >>= 1) { if (tid < s) red[tid] += red[tid + s]; __syncthreads(); }
  if (tid == 0) atomicAdd(loss_sum, red[0]);
  for (int j = tid; j < 512; j += 256) {
    int h = lhist[j];
    if (h > 0) atomicAdd(&counts[j], (float)h);
  }
}

// ---------------------------------------------------------------------------
// Decoder step D_k (k=1..21), grid 1280 (1281 at k=21):
//  blocks 0..511: rec h1_{k-1} (k<=20), o-split
//  blocks 512..1023: h1l_k GEMM (k<=19)
//  blocks 1024..1279: emit frame t=k-3 from global h1 state k-2 (k>=3)
//  block 1280 (k=21 only): finalize scalars
// ---------------------------------------------------------------------------
__global__ __launch_bounds__(256) void k_dec(
    int k, const float* __restrict__ h2all, const float* __restrict__ dw1,
    float* __restrict__ h1l_out,
    const float* __restrict__ h1_in, const float* __restrict__ h1l_in,
    const float* __restrict__ dr0, const float* __restrict__ dr0b,
    const float* __restrict__ dw1b, float* __restrict__ h1_out,
    const float* __restrict__ w0d, const float* __restrict__ w0db,
    float* __restrict__ outp, const float* __restrict__ h1_emit,
    const float* __restrict__ counts, const float* __restrict__ scal)
{
  int bid = blockIdx.x, tid = threadIdx.x;
  if (bid == 1280) {          // ---- finalize (k==21 only) ----
    __shared__ float red[256];
    float e = 0.f;
    for (int u = tid; u < 512; u += 256) {
      float avg = counts[u] * (1.0f / 16384.0f);
      e += avg * logf(avg + 1e-10f);
    }
    red[tid] = e;
    __syncthreads();
    for (int s = 128; s > 0; s >>= 1) { if (tid < s) red[tid] += red[tid + s]; __syncthreads(); }
    if (tid == 0) {
      outp[0] = 0.25f * scal[0] * (1.0f / 1048576.0f);
      outp[1] = scal[1] * (1.0f / 256.0f);
      outp[2 + 8404992] = expf(-red[0]);
    }
    return;
  }
  if (bid >= 1024) {          // ---- emit frame t = k-3 ----
    int t = k - 3;
    if (t < 0) return;
    int b = bid - 1024;
    int p = tid & 63;
    int mbase = RL(tid >> 6) * 7;
    const float* hg = h1_emit + b * 4096;
    float a[7];
    #pragma unroll
    for (int qq = 0; qq < 7; ++qq) a[qq] = 0.f;
    for (int c = 0; c < 64; ++c) {
      float hv = hg[c * 64 + p];               // coalesced
      const float* wr = w0d + c * 27 + mbase;  // uniform -> s_load
      #pragma unroll
      for (int qq = 0; qq < 7; ++qq)
        if (mbase + qq < 27) a[qq] += hv * wr[qq];
    }
    int hrow = p >> 3, wcol = p & 7;
    #pragma unroll
    for (int qq = 0; qq < 7; ++qq) {
      int m = mbase + qq;
      if (m < 27) {
        int o3 = m / 9, r = m % 9, ki = r / 3, kj = r % 3;
        float v = a[qq] + w0db[o3];
        v = v > 0.f ? v : expm1f(v);   // ELU alpha=1
        outp[2 + ((b * 19 + t) * 3 + o3) * 576 + (hrow * 3 + ki) * 24 + (wcol * 3 + kj)] = v;
      }
    }
    return;
  }
  if (bid >= 512) {           // ---- h1l_k GEMM ----
    if (k > 19) return;
    int cid = bid - 512;
    int nc = cid & 15, bt = cid >> 4;
    int n = nc * 256 + tid, b0 = bt * 8;
    const float* hp = h2all + k * 32768 + b0 * 128;
    float acc[8];
    #pragma unroll
    for (int q = 0; q < 8; ++q) acc[q] = 0.f;
    for (int j = 0; j < 128; j += 4) {
      float w0v = dw1[j * 4096 + n], w1v = dw1[(j+1) * 4096 + n];
      float w2v = dw1[(j+2) * 4096 + n], w3v = dw1[(j+3) * 4096 + n];
      #pragma unroll
      for (int q = 0; q < 8; ++q) {
        const float* hr = hp + q * 128 + j;    // uniform -> s_load
        acc[q] += hr[0] * w0v + hr[1] * w1v + hr[2] * w2v + hr[3] * w3v;
      }
    }
    float* ob = h1l_out + b0 * 4096 + n;
    #pragma unroll
    for (int q = 0; q < 8; ++q) ob[q * 4096] = acc[q];
    return;
  }
  // ---- rec: h1_{k-1} = relu(dr0.h1_{k-2} + h1l_{k-1} + biases), o-split ----
  if (k > 20) return;
  int b = bid >> 1, og = bid & 1;
  int p = tid & 63;
  int o0 = og * 32 + RL(tid >> 6) * 8;
  float acc[8];
  #pragma unroll
  for (int q = 0; q < 8; ++q) acc[q] = dr0b[o0 + q] + dw1b[o0 + q];
  const float* hb = h1_in + b * 4096 + p;
  for (int c = 0; c < 64; c += 4) {
    float h0 = hb[c * 64], h1v = hb[(c+1) * 64];
    float h2v = hb[(c+2) * 64], h3v = hb[(c+3) * 64];
    #pragma unroll
    for (int q = 0; q < 8; ++q) {
      const float* rr = dr0 + (o0 + q) * 64 + c;   // uniform -> s_load
      acc[q] += h0 * rr[0] + h1v * rr[1] + h2v * rr[2] + h3v * rr[3];
    }
  }
  const float* lb = h1l_in + b * 4096 + p;
  float* ob = h1_out + b * 4096 + p;
  #pragma unroll
  for (int q = 0; q < 8; ++q)
    ob[(o0 + q) * 64] = relu_(acc[q] + lb[(o0 + q) * 64]);
}

// ---------------------------------------------------------------------------
extern "C" void kernel_launch(void* const* d_in, const int* in_sizes, int n_in,
                              void* d_out, int out_size, void* d_ws, size_t ws_size,
                              hipStream_t stream)
{
  const float* x     = (const float*)d_in[0];
  const float* eps   = (const float*)d_in[1];
  const float* emb   = (const float*)d_in[2];
  const float* ew0   = (const float*)d_in[3];
  const float* ew0b  = (const float*)d_in[4];
  const float* ew1   = (const float*)d_in[5];
  const float* ew1b  = (const float*)d_in[6];
  const float* er0   = (const float*)d_in[7];
  const float* er0b  = (const float*)d_in[8];
  const float* elinw = (const float*)d_in[9];
  const float* elinb = (const float*)d_in[10];
  const float* dw0   = (const float*)d_in[11];
  const float* dw0b  = (const float*)d_in[12];
  const float* dw1   = (const float*)d_in[13];
  const float* dw1b  = (const float*)d_in[14];
  const float* dr0   = (const float*)d_in[15];
  const float* dr0b  = (const float*)d_in[16];
  const float* dlinw = (const float*)d_in[17];
  const float* dlinb = (const float*)d_in[18];
  float* out = (float*)d_out;
  float* ws  = (float*)d_ws;

  float* W1T    = ws + 0;        // 4096x256 (encoder)
  float* H2ALL  = ws + 0;        // 20x256x128 (decoder; overlays W1T)
  float* LINT   = ws + 1048576;  // 256x256
  float* DLINT  = ws + 1114112;  // 128x128
  float* EMBSQ  = ws + 1130496;  // 512
  float* H1A    = ws + 1131008;  // 256x4096
  float* H1B    = ws + 2179584;  // 256x4096
  float* Q      = ws + 3228160;  // 256x4096
  float* PARTS0 = ws + 4276736;  // 16x256x256
  float* PARTS1 = ws + 5325312;  // 16x256x256
  float* H1L0   = PARTS0;        // decoder overlay
  float* H1L1   = PARTS1;        // decoder overlay
  float* H2A    = ws + 6373888;  // 256x256
  float* H2B    = ws + 6439424;  // 256x256
  float* SCAL   = ws + 6504960;  // [0]=loss, [1]=kl
  float* COUNTS = ws + 6504962;  // 512
  float* PBEST  = ws + 6505474;  // 4x256x64
  int*   PIDX   = (int*)(ws + 6571010);  // 4x256x64

  k_prep<<<279, 256, 0, stream>>>(ew1, elinw, dlinw, emb, W1T, LINT, DLINT,
                                  EMBSQ, SCAL, COUNTS);

  // ---- encoder: E_t computes h1_t (split), contract_{t-1}, h2_{t-2} ----
  for (int t = 0; t < 20; ++t) {
    const float* h1i = (t & 1) ? H1A : H1B;
    float* h1o       = (t & 1) ? H1B : H1A;
    float* po        = ((t - 1) & 1) ? PARTS1 : PARTS0;
    const float* pi  = (t & 1) ? PARTS1 : PARTS0;
    float* h2o       = (t & 1) ? H2B : H2A;
    const float* h2i = (t & 1) ? H2A : H2B;
    k_enc<<<1024, 256, 0, stream>>>(x, t, ew0, ew0b, er0, er0b, h1i, h1o,
                                    W1T, po, pi, ew1b, LINT, elinb, h2i, h2o);
  }

  // ---- VQ argmin quarters + h2_18 epilogue ----
  k_argmin<<<1280, 256, 0, stream>>>(H1A, emb, EMBSQ, PARTS0, ew1b, LINT,
                                     elinb, H2B, H2A, PBEST, PIDX);
  // ---- KL + decoder h2 chain ----
  k_mid<<<256, 256, 0, stream>>>(H2A, eps, &SCAL[1], DLINT, dlinb, H2ALL);
  // ---- VQ stats + h1l_0 ----
  k_dec0<<<768, 256, 0, stream>>>(H1A, emb, PBEST, PIDX, Q, COUNTS, &SCAL[0],
                                  H2ALL, dw1, H1L0);

  // ---- decoder: D_k computes h1_{k-1}, h1l_k, frame k-3 ----
  for (int k = 1; k <= 21; ++k) {
    int s = k - 1;
    float* h1l_o       = (k & 1) ? H1L1 : H1L0;
    const float* h1l_i = (k & 1) ? H1L0 : H1L1;
    const float* h1i   = (s == 0) ? Q : (((s - 1) & 1) ? H1B : H1A);
    float* h1o         = (s & 1) ? H1B : H1A;
    const float* h1e   = (k >= 3) ? (((k - 2) & 1) ? H1B : H1A) : H1A;
    int grid = (k == 21) ? 1281 : 1280;
    k_dec<<<grid, 256, 0, stream>>>(k, H2ALL, dw1, h1l_o, h1i, h1l_i,
                                    dr0, dr0b, dw1b, h1o, dw0, dw0b, out,
                                    h1e, COUNTS, SCAL);
  }
}

// Round 8
// 1339.968 us; speedup vs baseline: 2.6292x; 1.0962x over previous
//
#include <hip/hip_runtime.h>
#include <math.h>

#define RL(x) __builtin_amdgcn_readfirstlane(x)

__device__ __forceinline__ float relu_(float v) { return v > 0.f ? v : 0.f; }
__device__ __forceinline__ unsigned short f2bf(float f) {
  unsigned u = __float_as_uint(f);
  u += 0x7FFFu + ((u >> 16) & 1u);           // round-to-nearest-even
  return (unsigned short)(u >> 16);
}
__device__ __forceinline__ float bf2f(unsigned short h) {
  return __uint_as_float((unsigned)h << 16);
}

// ---------------------------------------------------------------------------
// Prep: transposes (w1T, LINT, DLINT) + |emb|^2 + zero SCAL/COUNTS. grid 279.
// ---------------------------------------------------------------------------
__global__ __launch_bounds__(256) void k_prep(
    const float* __restrict__ w1, const float* __restrict__ linw,
    const float* __restrict__ dlinw, const float* __restrict__ emb,
    float* __restrict__ w1T, float* __restrict__ linT,
    float* __restrict__ dlinT, float* __restrict__ embsq,
    float* __restrict__ scal, float* __restrict__ counts)
{
  int bid = blockIdx.x;
  if (bid == 278) {
    if (threadIdx.x < 2) scal[threadIdx.x] = 0.f;
    for (int j = threadIdx.x; j < 512; j += 256) counts[j] = 0.f;
    return;
  }
  if (bid >= 276) {
    int k = (bid - 276) * 256 + threadIdx.x;
    const float* e = emb + k * 64;
    float s0 = 0, s1 = 0, s2 = 0, s3 = 0;
    #pragma unroll
    for (int c = 0; c < 64; c += 4) {
      s0 += e[c] * e[c]; s1 += e[c+1] * e[c+1];
      s2 += e[c+2] * e[c+2]; s3 += e[c+3] * e[c+3];
    }
    embsq[k] = (s0 + s1) + (s2 + s3);
    return;
  }
  __shared__ float buf[64 * 65];
  const float* in; float* out; int R, C, tr, tc;
  if (bid < 256)      { in = w1;    out = w1T;   R = 256; C = 4096; tr = bid >> 6;         tc = bid & 63; }
  else if (bid < 272) { in = linw;  out = linT;  R = 256; C = 256;  tr = (bid - 256) >> 2; tc = (bid - 256) & 3; }
  else                { in = dlinw; out = dlinT; R = 128; C = 128;  tr = (bid - 272) >> 1; tc = (bid - 272) & 1; }
  int r0 = tr * 64, c0 = tc * 64;
  int lane = threadIdx.x & 63, grp = threadIdx.x >> 6;
  for (int pp = 0; pp < 16; ++pp) {
    int rr = pp * 4 + grp;
    buf[rr * 65 + lane] = in[(r0 + rr) * C + c0 + lane];
  }
  __syncthreads();
  for (int pp = 0; pp < 16; ++pp) {
    int cc = pp * 4 + grp;
    out[(c0 + cc) * R + r0 + lane] = buf[lane * 65 + cc];
  }
}

// ---------------------------------------------------------------------------
// Encoder chain: 256 blocks (one batch each) run ALL 19 h1 steps with state
// in LDS. Stores each h1_t as bf16 (t<16 -> out-region, t>=16 -> ws tail) and
// the final h1_18 fp32 to H1F.
// ---------------------------------------------------------------------------
__global__ __launch_bounds__(256) void k_encchain(
    const float* __restrict__ x,
    const float* __restrict__ w0, const float* __restrict__ w0b,
    const float* __restrict__ r0, const float* __restrict__ r0b,
    unsigned short* __restrict__ st_out,   // 16 states x 1,048,576 bf16
    unsigned short* __restrict__ st_tail,  // 3 states
    float* __restrict__ h1f)
{
  __shared__ float stA[4096];
  __shared__ float stB[4096];
  int b = blockIdx.x, tid = threadIdx.x;
  int p = tid & 63;
  int o0 = RL(tid >> 6) * 16;
  float* cur = stA;
  float* nxt = stB;

  for (int t = 0; t <= 18; ++t) {
    // conv0(x_t) for this thread's 16 output rows
    int i = p >> 3, j = p & 7;
    const float* xb = x + ((size_t)(b * 19 + t) * 3) * 576 + (i * 3) * 24 + j * 3;
    float xv[27];
    #pragma unroll
    for (int c = 0; c < 3; ++c)
      #pragma unroll
      for (int ki = 0; ki < 3; ++ki)
        #pragma unroll
        for (int kj = 0; kj < 3; ++kj)
          xv[c * 9 + ki * 3 + kj] = xb[c * 576 + ki * 24 + kj];
    float acc[16];
    #pragma unroll
    for (int q = 0; q < 16; ++q) {
      float a = w0b[o0 + q] + (t > 0 ? r0b[o0 + q] : 0.f);
      const float* wr = w0 + (o0 + q) * 27;     // wave-uniform -> s_load
      float c0 = 0, c1 = 0, c2 = 0;
      #pragma unroll
      for (int m = 0; m < 27; m += 3) {
        c0 += xv[m] * wr[m]; c1 += xv[m+1] * wr[m+1]; c2 += xv[m+2] * wr[m+2];
      }
      acc[q] = a + c0 + c1 + c2;
    }
    if (t > 0) {
      for (int c = 0; c < 64; c += 4) {
        float h0 = cur[c * 64 + p],     h1v = cur[(c+1) * 64 + p];
        float h2v = cur[(c+2) * 64 + p], h3v = cur[(c+3) * 64 + p];
        #pragma unroll
        for (int q = 0; q < 16; ++q) {
          const float* rr = r0 + (o0 + q) * 64 + c;  // uniform -> s_load_x4
          acc[q] += h0 * rr[0] + h1v * rr[1] + h2v * rr[2] + h3v * rr[3];
        }
      }
    }
    unsigned short* so = (t < 16)
        ? st_out  + (size_t)t * 1048576 + (size_t)b * 4096
        : st_tail + (size_t)(t - 16) * 1048576 + (size_t)b * 4096;
    #pragma unroll
    for (int q = 0; q < 16; ++q) {
      float v = relu_(acc[q]);
      nxt[(o0 + q) * 64 + p] = v;
      so[(o0 + q) * 64 + p] = f2bf(v);
      if (t == 18) h1f[(size_t)b * 4096 + (o0 + q) * 64 + p] = v;
    }
    __syncthreads();
    float* tmp = cur; cur = nxt; nxt = tmp;
    __syncthreads();
  }
}

// ---------------------------------------------------------------------------
// All 19 contracts in one dispatch: parts[t][b][o] = flat(h1_t[b]) . w1[o]
// grid 19*32 = 608 blocks (t, 8-batch tile), 256 thr (o). A via scalar uint
// loads (bf16 pairs), W via coalesced vector loads of w1T.
// ---------------------------------------------------------------------------
__global__ __launch_bounds__(256) void k_contract(
    const unsigned short* __restrict__ st_out,
    const unsigned short* __restrict__ st_tail,
    const float* __restrict__ w1T, float* __restrict__ parts)
{
  int bid = blockIdx.x, o = threadIdx.x;
  int t = bid >> 5, bt = bid & 31;
  int b0 = bt * 8;
  const unsigned short* sbase = (t < 16)
      ? st_out  + (size_t)t * 1048576
      : st_tail + (size_t)(t - 16) * 1048576;
  const unsigned* sp[8];
  #pragma unroll
  for (int q = 0; q < 8; ++q)
    sp[q] = (const unsigned*)(sbase + (size_t)(b0 + q) * 4096);
  float acc[8];
  #pragma unroll
  for (int q = 0; q < 8; ++q) acc[q] = 0.f;
  for (int k = 0; k < 4096; k += 4) {
    float w0v = w1T[(k    ) * 256 + o], w1v = w1T[(k + 1) * 256 + o];
    float w2v = w1T[(k + 2) * 256 + o], w3v = w1T[(k + 3) * 256 + o];
    #pragma unroll
    for (int q = 0; q < 8; ++q) {
      unsigned va = sp[q][(k >> 1)    ];     // uniform -> s_load
      unsigned vb = sp[q][(k >> 1) + 1];
      float a0 = __uint_as_float(va << 16);
      float a1 = __uint_as_float(va & 0xFFFF0000u);
      float a2 = __uint_as_float(vb << 16);
      float a3 = __uint_as_float(vb & 0xFFFF0000u);
      acc[q] += a0 * w0v + a1 * w1v + a2 * w2v + a3 * w3v;
    }
  }
  float* pb = parts + (size_t)t * 65536 + (size_t)b0 * 256 + o;
  #pragma unroll
  for (int q = 0; q < 8; ++q) pb[q * 256] = acc[q];
}

// ---------------------------------------------------------------------------
// Full h2 pipeline in one dispatch: 256 blocks (1/batch) x 512 threads.
// Enc h2 chain (19 steps, LINT rows register-resident, K-split 2), then
// KL + reparam, then dec h2 chain (20 steps, DLINT register-resident).
// ---------------------------------------------------------------------------
__global__ __launch_bounds__(512, 1) void k_h2all(
    const float* __restrict__ parts, const float* __restrict__ w1b,
    const float* __restrict__ linT, const float* __restrict__ linb,
    const float* __restrict__ eps, float* __restrict__ scal,
    const float* __restrict__ dlinT, const float* __restrict__ dlinb,
    float* __restrict__ h2alld)
{
  __shared__ float curL[256];
  __shared__ float ppart[512];
  __shared__ float red[256];
  int b = blockIdx.x, tid = threadIdx.x;
  int o  = tid & 255, kh = tid >> 8;         // enc roles
  float wreg[128];
  #pragma unroll
  for (int jj = 0; jj < 128; ++jj)
    wreg[jj] = linT[(kh * 128 + jj) * 256 + o];

  // t = 0: h2_0 = relu(h2h_0)
  if (tid < 256)
    curL[tid] = relu_(parts[(size_t)b * 256 + tid] + w1b[tid]);
  __syncthreads();
  // t = 1..18
  for (int t = 1; t <= 18; ++t) {
    float lacc = 0.f;
    #pragma unroll
    for (int jj = 0; jj < 128; ++jj)
      lacc += wreg[jj] * curL[kh * 128 + jj];   // LDS broadcast
    ppart[tid] = lacc;
    __syncthreads();
    float v = 0.f;
    if (tid < 256) {
      float h2h = relu_(parts[(size_t)t * 65536 + (size_t)b * 256 + tid] + w1b[tid]);
      v = relu_(h2h + ppart[tid] + ppart[256 + tid] + linb[tid]);
    }
    __syncthreads();
    if (tid < 256) curL[tid] = v;
    __syncthreads();
  }
  // KL + reparam (h2_18 in curL)
  if (tid < 128) {
    float mu = curL[tid], lv = curL[128 + tid];
    red[tid] = 0.5f * (expf(lv) + mu * mu - 1.0f - lv);
  }
  __syncthreads();
  for (int s = 64; s > 0; s >>= 1) {
    if (tid < s) red[tid] += red[tid + s];
    __syncthreads();
  }
  if (tid == 0) atomicAdd(&scal[1], red[0]);
  float hs = 0.f;
  if (tid < 128)
    hs = curL[tid] + expf(0.5f * curL[128 + tid]) * eps[(size_t)b * 128 + tid];
  __syncthreads();
  if (tid < 128) curL[tid] = hs;              // cur2 = h2s (128 entries)
  __syncthreads();

  // dec h2 chain: 20 steps, threads 0..255 = (o2 = tid&127, kh2 = tid>>7)
  int o2 = tid & 127, kh2 = (tid >> 7) & 1;
  float wreg2[64];
  if (tid < 256) {
    #pragma unroll
    for (int jj = 0; jj < 64; ++jj)
      wreg2[jj] = dlinT[(kh2 * 64 + jj) * 128 + o2];
  }
  for (int s = 0; s < 20; ++s) {
    float lacc = 0.f;
    if (tid < 256) {
      #pragma unroll
      for (int jj = 0; jj < 64; ++jj)
        lacc += wreg2[jj] * curL[kh2 * 64 + jj];
      ppart[tid] = lacc;
    }
    __syncthreads();
    float v = 0.f;
    if (tid < 128) {
      v = relu_(ppart[tid] + ppart[128 + tid] + dlinb[tid]);
      h2alld[(size_t)s * 32768 + (size_t)b * 128 + tid] = v;
    }
    __syncthreads();
    if (tid < 128) curL[tid] = v;
    __syncthreads();
  }
}

// ---------------------------------------------------------------------------
// VQ argmin quarters: grid 1024 (qtr = bid>>8, b = bid&255), from fp32 h1_18.
// ---------------------------------------------------------------------------
__global__ __launch_bounds__(256) void k_argmin(
    const float* __restrict__ h1f, const float* __restrict__ emb,
    const float* __restrict__ embsq,
    float* __restrict__ pbest, int* __restrict__ pidx)
{
  __shared__ float sd[256];
  __shared__ int   sk[256];
  int bid = blockIdx.x, tid = threadIdx.x;
  int qtr = bid >> 8, b = bid & 255;
  int p = tid & 63, kg = RL(tid >> 6);
  float f[64];
  const float* hb = h1f + (size_t)b * 4096 + p;
  #pragma unroll
  for (int c = 0; c < 64; ++c) f[c] = hb[c * 64];
  float best = 3.4e38f; int bk = 0;
  int kbeg = qtr * 128 + kg * 32;
  for (int k = kbeg; k < kbeg + 32; ++k) {
    const float* er = emb + k * 64;            // uniform -> s_load
    float d0 = 0, d1 = 0, d2 = 0, d3 = 0;
    #pragma unroll
    for (int c = 0; c < 64; c += 4) {
      d0 += f[c] * er[c];     d1 += f[c+1] * er[c+1];
      d2 += f[c+2] * er[c+2]; d3 += f[c+3] * er[c+3];
    }
    float d = embsq[k] - 2.f * ((d0 + d1) + (d2 + d3));
    if (d < best) { best = d; bk = k; }
  }
  sd[tid] = best; sk[tid] = bk;
  __syncthreads();
  if (tid < 64) {
    float bb = sd[tid]; int kk = sk[tid];
    #pragma unroll
    for (int g = 1; g < 4; ++g) {
      float dg = sd[g * 64 + tid];
      if (dg < bb) { bb = dg; kk = sk[g * 64 + tid]; }
    }
    pbest[qtr * 16384 + b * 64 + tid] = bb;
    pidx [qtr * 16384 + b * 64 + tid] = kk;
  }
}

// ---------------------------------------------------------------------------
// h1l placement: step d's projection, bf16.
//  d in 1..17  -> inside out-frames (b, d-1..d)  [overwritten only at steps
//                 d+1/d+2, after consumption at step d]
//  d in {0,18,19} -> ws tail slots 0..2
// ---------------------------------------------------------------------------
__device__ __forceinline__ unsigned short* h1l_ptr(
    int d, int b, float* out, unsigned short* tail)
{
  if (d >= 1 && d <= 17)
    return (unsigned short*)(out + 2 + (size_t)b * 32832 + (size_t)(d - 1) * 1728);
  int slot = (d == 0) ? 0 : (d - 17);
  return tail + (size_t)slot * 1048576 + (size_t)b * 4096;
}

// ---------------------------------------------------------------------------
// All 20 h1l GEMMs + VQ stats in one dispatch.
//  blocks 0..1279: (d = bid/64, nc = (bid%64)>>2, bq = bid&3): 64 batches,
//                  n = nc*256+tid, K=128.
//  blocks 1280..1535: stats for batch b (merge quarters, Q, loss, histogram)
// ---------------------------------------------------------------------------
__global__ __launch_bounds__(256) void k_dec0(
    const float* __restrict__ h1f, const float* __restrict__ emb,
    const float* __restrict__ pbest, const int* __restrict__ pidx,
    float* __restrict__ Q, float* __restrict__ counts,
    float* __restrict__ loss_sum,
    const float* __restrict__ h2alld, const float* __restrict__ dw1,
    float* __restrict__ out, unsigned short* __restrict__ tail)
{
  int bid = blockIdx.x, tid = threadIdx.x;
  if (bid < 1280) {            // ---- h1l for all steps ----
    int d = bid >> 6, r = bid & 63;
    int nc = r >> 2, bq = r & 3;
    int n = nc * 256 + tid;
    #pragma unroll 1
    for (int ch = 0; ch < 4; ++ch) {
      int b0 = bq * 64 + ch * 16;
      const float* hp = h2alld + (size_t)d * 32768 + (size_t)b0 * 128;
      float acc[16];
      #pragma unroll
      for (int q = 0; q < 16; ++q) acc[q] = 0.f;
      for (int j = 0; j < 128; j += 2) {
        float w0v = dw1[(size_t)j * 4096 + n];
        float w1v = dw1[(size_t)(j + 1) * 4096 + n];
        #pragma unroll
        for (int q = 0; q < 16; ++q) {
          const float* hr = hp + q * 128 + j;  // uniform -> s_load
          acc[q] += hr[0] * w0v + hr[1] * w1v;
        }
      }
      #pragma unroll
      for (int q = 0; q < 16; ++q)
        h1l_ptr(d, b0 + q, out, tail)[n] = f2bf(acc[q]);
    }
    return;
  }
  // ---- VQ stats ----
  __shared__ int   fk[64];
  __shared__ int   lhist[512];
  __shared__ float red[256];
  int b = bid - 1280;
  for (int j = tid; j < 512; j += 256) lhist[j] = 0;
  __syncthreads();
  if (tid < 64) {
    float bb = pbest[b * 64 + tid];
    int   kk = pidx [b * 64 + tid];
    #pragma unroll
    for (int q = 1; q < 4; ++q) {
      float dq = pbest[q * 16384 + b * 64 + tid];
      if (dq < bb) { bb = dq; kk = pidx[q * 16384 + b * 64 + tid]; }
    }
    fk[tid] = kk;
    atomicAdd(&lhist[kk], 1);
  }
  __syncthreads();
  int p = tid & 63, cgi = tid >> 6;
  int kk = fk[p];
  const float* eb = emb + kk * 64 + cgi * 16;
  const float* hz = h1f + (size_t)b * 4096 + cgi * 1024 + p;
  float* qb = Q + (size_t)b * 4096 + cgi * 1024 + p;
  float ls = 0;
  #pragma unroll
  for (int c = 0; c < 16; ++c) {
    float e = eb[c];
    float z = hz[c * 64];
    float dd = e - z;
    ls += dd * dd;
    qb[c * 64] = e;
  }
  red[tid] = ls;
  __syncthreads();
  for (int s = 128; s > 0; s >>= 1) { if (tid < s) red[tid] += red[tid + s]; __syncthreads(); }
  if (tid == 0) atomicAdd(loss_sum, red[0]);
  for (int j = tid; j < 512; j += 256) {
    int h = lhist[j];
    if (h > 0) atomicAdd(&counts[j], (float)h);
  }
}

// ---------------------------------------------------------------------------
// Decoder chain: 256 blocks (one batch) run ALL 20 h1 steps in LDS, emitting
// frames 0..18 (frame d-1 at step d). Block 256 finalizes scalars.
// ---------------------------------------------------------------------------
__global__ __launch_bounds__(256) void k_decchain(
    const float* __restrict__ Q,
    const float* __restrict__ dr0, const float* __restrict__ dr0b,
    const float* __restrict__ dw1b,
    const float* __restrict__ w0d, const float* __restrict__ w0db,
    float* __restrict__ out, unsigned short* __restrict__ tail,
    const float* __restrict__ counts, const float* __restrict__ scal)
{
  int bid = blockIdx.x, tid = threadIdx.x;
  if (bid == 256) {            // ---- finalize ----
    __shared__ float red[256];
    float e = 0.f;
    for (int u = tid; u < 512; u += 256) {
      float avg = counts[u] * (1.0f / 16384.0f);
      e += avg * logf(avg + 1e-10f);
    }
    red[tid] = e;
    __syncthreads();
    for (int s = 128; s > 0; s >>= 1) { if (tid < s) red[tid] += red[tid + s]; __syncthreads(); }
    if (tid == 0) {
      out[0] = 0.25f * scal[0] * (1.0f / 1048576.0f);
      out[1] = scal[1] * (1.0f / 256.0f);
      out[2 + 8404992] = expf(-red[0]);
    }
    return;
  }
  __shared__ float stA[4096];
  __shared__ float stB[4096];
  int b = bid;
  int p = tid & 63;
  int o0 = RL(tid >> 6) * 16;
  for (int idx = tid; idx < 4096; idx += 256)
    stA[idx] = Q[(size_t)b * 4096 + idx];
  __syncthreads();
  float* cur = stA;
  float* nxt = stB;

  for (int d = 0; d <= 19; ++d) {
    const unsigned short* lp = h1l_ptr(d, b, out, tail);
    float acc[16];
    #pragma unroll
    for (int q = 0; q < 16; ++q)
      acc[q] = dr0b[o0 + q] + dw1b[o0 + q] + bf2f(lp[(o0 + q) * 64 + p]);
    for (int c = 0; c < 64; c += 4) {
      float h0 = cur[c * 64 + p],     h1v = cur[(c+1) * 64 + p];
      float h2v = cur[(c+2) * 64 + p], h3v = cur[(c+3) * 64 + p];
      #pragma unroll
      for (int q = 0; q < 16; ++q) {
        const float* rr = dr0 + (o0 + q) * 64 + c;   // uniform -> s_load_x4
        acc[q] += h0 * rr[0] + h1v * rr[1] + h2v * rr[2] + h3v * rr[3];
      }
    }
    #pragma unroll
    for (int q = 0; q < 16; ++q)
      nxt[(o0 + q) * 64 + p] = relu_(acc[q]);
    __syncthreads();
    int t = d - 1;               // emit frame from the NEW state
    if (t >= 0) {
      int mbase = RL(tid >> 6) * 7;
      float a[7];
      #pragma unroll
      for (int qq = 0; qq < 7; ++qq) a[qq] = 0.f;
      for (int c = 0; c < 64; ++c) {
        float hv = nxt[c * 64 + p];
        const float* wr = w0d + c * 27 + mbase;      // uniform -> s_load
        #pragma unroll
        for (int qq = 0; qq < 7; ++qq)
          if (mbase + qq < 27) a[qq] += hv * wr[qq];
      }
      int hrow = p >> 3, wcol = p & 7;
      #pragma unroll
      for (int qq = 0; qq < 7; ++qq) {
        int m = mbase + qq;
        if (m < 27) {
          int o3 = m / 9, r = m % 9, ki = r / 3, kj = r % 3;
          float v = a[qq] + w0db[o3];
          v = v > 0.f ? v : expm1f(v);               // ELU alpha=1
          out[2 + ((size_t)(b * 19 + t) * 3 + o3) * 576 + (hrow * 3 + ki) * 24 + (wcol * 3 + kj)] = v;
        }
      }
    }
    __syncthreads();
    float* tmp = cur; cur = nxt; nxt = tmp;
  }
}

// ---------------------------------------------------------------------------
extern "C" void kernel_launch(void* const* d_in, const int* in_sizes, int n_in,
                              void* d_out, int out_size, void* d_ws, size_t ws_size,
                              hipStream_t stream)
{
  const float* x     = (const float*)d_in[0];
  const float* eps   = (const float*)d_in[1];
  const float* emb   = (const float*)d_in[2];
  const float* ew0   = (const float*)d_in[3];
  const float* ew0b  = (const float*)d_in[4];
  const float* ew1   = (const float*)d_in[5];
  const float* ew1b  = (const float*)d_in[6];
  const float* er0   = (const float*)d_in[7];
  const float* er0b  = (const float*)d_in[8];
  const float* elinw = (const float*)d_in[9];
  const float* elinb = (const float*)d_in[10];
  const float* dw0   = (const float*)d_in[11];
  const float* dw0b  = (const float*)d_in[12];
  const float* dw1   = (const float*)d_in[13];
  const float* dw1b  = (const float*)d_in[14];
  const float* dr0   = (const float*)d_in[15];
  const float* dr0b  = (const float*)d_in[16];
  const float* dlinw = (const float*)d_in[17];
  const float* dlinb = (const float*)d_in[18];
  float* out = (float*)d_out;
  float* ws  = (float*)d_ws;

  // ws layout (floats), total ~5.65M floats = 22.6 MB:
  float* W1T    = ws + 0;          // 4096x256; Q overlays after contract
  float* Q      = ws + 0;
  float* LINT   = ws + 1048576;    // 256x256 (j-major)
  float* DLINT  = ws + 1114112;    // 128x128 (j-major)
  float* EMBSQ  = ws + 1130496;    // 512
  float* H1F    = ws + 1131008;    // 256x4096 fp32 h1_18
  float* PARTS  = ws + 2179584;    // 19x256x256 h2h pre-bias
  float* PBEST  = ws + 2179584;    // overlays PARTS (argmin after h2all)
  int*   PIDX   = (int*)(ws + 2245120);
  unsigned short* TAIL = (unsigned short*)(ws + 3424768); // 3x1,048,576 bf16
  float* H2ALLD = ws + 4997632;    // 20x256x128
  float* SCAL   = ws + 5652992;    // [0]=loss, [1]=kl
  float* COUNTS = ws + 5652994;    // 512

  unsigned short* ST_OUT = (unsigned short*)(out + 2);  // 16 bf16 h1 states

  k_prep<<<279, 256, 0, stream>>>(ew1, elinw, dlinw, emb, W1T, LINT, DLINT,
                                  EMBSQ, SCAL, COUNTS);
  k_encchain<<<256, 256, 0, stream>>>(x, ew0, ew0b, er0, er0b,
                                      ST_OUT, TAIL, H1F);
  k_contract<<<608, 256, 0, stream>>>(ST_OUT, TAIL, W1T, PARTS);
  k_h2all<<<256, 512, 0, stream>>>(PARTS, ew1b, LINT, elinb, eps, SCAL,
                                   DLINT, dlinb, H2ALLD);
  k_argmin<<<1024, 256, 0, stream>>>(H1F, emb, EMBSQ, PBEST, PIDX);
  k_dec0<<<1536, 256, 0, stream>>>(H1F, emb, PBEST, PIDX, Q, COUNTS, &SCAL[0],
                                   H2ALLD, dw1, out, TAIL);
  k_decchain<<<257, 256, 0, stream>>>(Q, dr0, dr0b, dw1b, dw0, dw0b,
                                      out, TAIL, COUNTS, SCAL);
}